// Round 6
// baseline (569.115 us; speedup 1.0000x reference)
//
#include <hip/hip_runtime.h>
#include <hip/hip_bf16.h>

#define NODES 32768
#define HD 128
#define NE 524288
#define NR 8

typedef unsigned int u32;
typedef unsigned short u16;
typedef __attribute__((ext_vector_type(8))) short bf16x8;
typedef __attribute__((ext_vector_type(4))) float f32x4;

// ---- ws byte offsets ----
#define XH_OFF   (0u)                      // bf16 hi, 8 MB (reused both layers)
#define XL_OFF   (8u<<20)                  // bf16 lo, 8 MB
#define Y_OFF    (16u<<20)                 // bf16 y[8][NODES][128], 64 MB
#define Z_OFF    (80u<<20)                 // fp32 z[NODES][128], 16 MB
#define ADJ_OFF  (96u<<20)                 // u32 x NE
#define RP_OFF   (98u<<20)                 // u32 x (NODES+1)
#define CUR_OFF  ((98u<<20)+(256u<<10))    // u32 x NODES
#define BSUM_OFF ((98u<<20)+(512u<<10))    // u32 x 128
#define BP_OFF   ((98u<<20)+(640u<<10))    // packed weights bf16: 2 layers x 9 tiles x 2 segs x 16384

#define BP_LAYER 294912                    // 9*2*16384

__device__ __forceinline__ float bflo(u32 u){ union{u32 i;float f;}c; c.i=u<<16; return c.f; }
__device__ __forceinline__ float bfhi(u32 u){ union{u32 i;float f;}c; c.i=u&0xffff0000u; return c.f; }
__device__ __forceinline__ u16 f2bf(float f){
  u32 u=__float_as_uint(f);
  u32 r=u + 0x7fffu + ((u>>16)&1u);
  return (u16)(r>>16);
}
__device__ __forceinline__ float bf2f(u16 h){ return __uint_as_float(((u32)h)<<16); }

__device__ __forceinline__ void gl_lds16(const void* g, void* l){
  __builtin_amdgcn_global_load_lds((const __attribute__((address_space(1))) u32*)g,
                                   (__attribute__((address_space(3))) u32*)l, 16, 0, 0);
}

// ---------------- embed + projection GEMM (fp32 vector) ----------------
__device__ __forceinline__ void fma64(const float* At, const float* Wt,
                                      int mq, int gq, float acc[8][4])
{
#pragma unroll 8
  for(int kk=0;kk<64;kk++){
    const float4 a0=*(const float4*)&At[kk*68+mq*8];
    const float4 a1=*(const float4*)&At[kk*68+mq*8+4];
    const float4 w =*(const float4*)&Wt[kk*132+gq*4];
    float av[8]={a0.x,a0.y,a0.z,a0.w,a1.x,a1.y,a1.z,a1.w};
#pragma unroll
    for(int i=0;i<8;i++){
      acc[i][0]=fmaf(av[i],w.x,acc[i][0]);
      acc[i][1]=fmaf(av[i],w.y,acc[i][1]);
      acc[i][2]=fmaf(av[i],w.z,acc[i][2]);
      acc[i][3]=fmaf(av[i],w.w,acc[i][3]);
    }
  }
}

__global__ __launch_bounds__(256) void embed_gemm(
    const int* __restrict__ cid, const int* __restrict__ kid,
    const float* __restrict__ cemb, const float* __restrict__ kemb,
    const float* __restrict__ pW, const float* __restrict__ pb,
    u16* __restrict__ xh, u16* __restrict__ xl)
{
  __shared__ float At[64*68];
  __shared__ float Wt[64*132];
  const int tid=threadIdx.x;
  const int d0=blockIdx.x*64;
  const int mq=tid>>5, gq=tid&31;
  float acc[8][4];
#pragma unroll
  for(int i=0;i<8;i++){ acc[i][0]=0.f; acc[i][1]=0.f; acc[i][2]=0.f; acc[i][3]=0.f; }

  for(int c=0;c<2;c++){
    const int h0=c*64;
    __syncthreads();
    { int m=tid>>2; int hh=(tid&3)*16;
      int ci=cid[d0+m], ki=kid[d0+m];
      const float* cp=cemb+(size_t)ci*HD+h0+hh;
      const float* kp=kemb+(size_t)ki*HD+h0+hh;
      float* ap=&At[hh*68+m];
#pragma unroll
      for(int j=0;j<16;j+=4){
        float4 a=*(const float4*)(cp+j);
        float4 b=*(const float4*)(kp+j);
        ap[(j+0)*68]=a.x+b.x; ap[(j+1)*68]=a.y+b.y;
        ap[(j+2)*68]=a.z+b.z; ap[(j+3)*68]=a.w+b.w;
      }
    }
    { int g=tid>>1; int hh=(tid&1)*32;
      const float* wp=pW+(size_t)g*HD+h0+hh;
      float* wl=&Wt[hh*132+g];
#pragma unroll
      for(int j=0;j<32;j+=4){
        float4 w=*(const float4*)(wp+j);
        wl[(j+0)*132]=w.x; wl[(j+1)*132]=w.y; wl[(j+2)*132]=w.z; wl[(j+3)*132]=w.w;
      }
    }
    __syncthreads();
    fma64(At,Wt,mq,gq,acc);
  }
  const float4 bias=*(const float4*)&pb[gq*4];
#pragma unroll
  for(int i=0;i<8;i++){
    int m=d0+mq*8+i;
    float v[4]={acc[i][0]+bias.x,acc[i][1]+bias.y,acc[i][2]+bias.z,acc[i][3]+bias.w};
    u16 hb[4], lb[4];
#pragma unroll
    for(int j=0;j<4;j++){ hb[j]=f2bf(v[j]); lb[j]=f2bf(v[j]-bf2f(hb[j])); }
    uint2 hv={(u32)hb[0]|((u32)hb[1]<<16),(u32)hb[2]|((u32)hb[3]<<16)};
    uint2 lv={(u32)lb[0]|((u32)lb[1]<<16),(u32)lb[2]|((u32)lb[3]<<16)};
    *(uint2*)&xh[(size_t)m*HD+gq*4]=hv;
    *(uint2*)&xl[(size_t)m*HD+gq*4]=lv;
  }
}

// ---------------- weight prep: per layer, 9 n-tiles (8 relations + self), hi/lo segs,
// MFMA-fragment-contiguous: k = ks32*32 + q*8 + j -> (ks32*128+n)*32 + q*8 + j
__global__ void prep_w(const float* __restrict__ rW, const float* __restrict__ sW,
                       u16* __restrict__ Bp)
{
  int idx=blockIdx.x*256+threadIdx.x;           // 2 * 9 * 16384 = 294912 total
  int l=idx/147456;
  int rem=idx%147456;
  int t=rem>>14;
  int kn=rem&16383;
  int k=kn>>7, n=kn&127;
  float w;
  if(t<8) w=rW[(((size_t)l*NR+t)*HD+n)*HD+k];
  else    w=sW[((size_t)l*HD+n)*HD+k];
  u16* base=Bp+(size_t)l*BP_LAYER+(size_t)t*32768;
  int ks=k>>5, q=(k>>3)&3, j=k&7;
  size_t off=((size_t)ks*128+n)*32+q*8+j;
  u16 hb=f2bf(w);
  u16 lb=f2bf(w-bf2f(hb));
  base[off]=hb;
  base[off+16384]=lb;
}

// ---------------- CSR build ----------------
__global__ void count_deg(const int* __restrict__ dst, u32* __restrict__ cnt){
  int e=blockIdx.x*256+threadIdx.x;
  atomicAdd(&cnt[dst[e]],1u);
}

__global__ void scan1(const u32* __restrict__ cnt, u32* __restrict__ rp, u32* __restrict__ bsum){
  __shared__ u32 sh[256];
  int t=threadIdx.x; int base=blockIdx.x*256;
  u32 v=cnt[base+t]; sh[t]=v; __syncthreads();
  for(int off=1;off<256;off<<=1){
    u32 tv=(t>=off)?sh[t-off]:0u; __syncthreads();
    sh[t]+=tv; __syncthreads();
  }
  rp[base+t]=sh[t]-v;
  if(t==255) bsum[blockIdx.x]=sh[255];
}

__global__ void scan2(u32* __restrict__ bsum, u32* __restrict__ rp){
  __shared__ u32 sh[128];
  int t=threadIdx.x;
  u32 v=bsum[t]; sh[t]=v; __syncthreads();
  for(int off=1;off<128;off<<=1){
    u32 tv=(t>=off)?sh[t-off]:0u; __syncthreads();
    sh[t]+=tv; __syncthreads();
  }
  bsum[t]=sh[t]-v;
  if(t==0) rp[NODES]=NE;
}

__global__ void scan3(u32* __restrict__ rp, const u32* __restrict__ bsum){
  int i=blockIdx.x*256+threadIdx.x;
  rp[i]+=bsum[blockIdx.x];
}

__global__ void scatter_edges(const int* __restrict__ src, const int* __restrict__ dst,
                              const int* __restrict__ et, const u32* __restrict__ rp,
                              u32* __restrict__ cur, u32* __restrict__ adj){
  int e=blockIdx.x*256+threadIdx.x;
  int d=dst[e];
  u32 pos=atomicAdd(&cur[d],1u);
  adj[rp[d]+pos]=(u32)src[e] | ((u32)et[e]<<16);
}

// ---------------- gemm_y: 64-row tile, 3 t's per block, stage once ----------------
// y[t] = x @ W_t^T (t<8, bf16 out), z = x @ selfW^T (t==8, fp32 out)
// grid (NODES/64, 3); block 256 = 4 waves (2 row-halves x 2 col-halves)
// LDS: xhi 16 KB + xlo 16 KB, staged together, ONE barrier per block
__global__ __launch_bounds__(256,4) void gemm_y(
    const u16* __restrict__ xhi, const u16* __restrict__ xlo,
    const u16* __restrict__ Bt, u16* __restrict__ y, float* __restrict__ z)
{
  __shared__ u16 Atile[2][64*128];   // [0]=xhi, [1]=xlo; row=256B, 16B-chunk XOR-16 swizzle
  const int tid=threadIdx.x;
  const int wave=tid>>6, lane=tid&63;
  const int wm=wave>>1, wn=wave&1;
  const int q=lane>>4;
  const int d0=blockIdx.x*64;

  const int st_c  = lane&15;        // dest 16B chunk within row
  const int st_rin= lane>>4;        // row within 4-row issue

  // ---- stage xhi + xlo (each wave: rows wave*16..+16 of both), one barrier ----
#pragma unroll
  for(int i=0;i<4;i++){
    int rbase=wave*16+i*4;
    int r=rbase+st_rin;
    int g=st_c ^ (r&15);
    gl_lds16(xhi+(size_t)(d0+r)*HD+g*8, &Atile[0][rbase*128]);
  }
#pragma unroll
  for(int i=0;i<4;i++){
    int rbase=wave*16+i*4;
    int r=rbase+st_rin;
    int g=st_c ^ (r&15);
    gl_lds16(xlo+(size_t)(d0+r)*HD+g*8, &Atile[1][rbase*128]);
  }
  __syncthreads();

  for(int tt=0;tt<3;tt++){
    const int t=blockIdx.y*3+tt;
    const u16* Btile=Bt+(size_t)t*32768;
    f32x4 acc[2][4];
#pragma unroll
    for(int a=0;a<2;a++)
#pragma unroll
      for(int b=0;b<4;b++) acc[a][b]=(f32x4){0.f,0.f,0.f,0.f};

    // ---- part 0: xhi @ {Whi, Wlo} ----
#pragma unroll
    for(int ks=0;ks<4;ks++){
      bf16x8 afr[2];
#pragma unroll
      for(int tm=0;tm<2;tm++){
        int m=wm*32+tm*16+(lane&15);
        afr[tm]=*(const bf16x8*)&Atile[0][m*128+(((ks*4)+q)^(m&15))*8];
      }
#pragma unroll
      for(int s=0;s<2;s++){
        const u16* Bb=Btile+s*16384;
#pragma unroll
        for(int tn=0;tn<4;tn++){
          int n=wn*64+tn*16+(lane&15);
          bf16x8 bfr=*(const bf16x8*)&Bb[((size_t)ks*128+n)*32+q*8];
#pragma unroll
          for(int tm=0;tm<2;tm++)
            acc[tm][tn]=__builtin_amdgcn_mfma_f32_16x16x32_bf16(afr[tm],bfr,acc[tm][tn],0,0,0);
        }
      }
    }

    // ---- part 1: xlo @ Whi ----
#pragma unroll
    for(int ks=0;ks<4;ks++){
      bf16x8 afr[2];
#pragma unroll
      for(int tm=0;tm<2;tm++){
        int m=wm*32+tm*16+(lane&15);
        afr[tm]=*(const bf16x8*)&Atile[1][m*128+(((ks*4)+q)^(m&15))*8];
      }
#pragma unroll
      for(int tn=0;tn<4;tn++){
        int n=wn*64+tn*16+(lane&15);
        bf16x8 bfr=*(const bf16x8*)&Btile[((size_t)ks*128+n)*32+q*8];
#pragma unroll
        for(int tm=0;tm<2;tm++)
          acc[tm][tn]=__builtin_amdgcn_mfma_f32_16x16x32_bf16(afr[tm],bfr,acc[tm][tn],0,0,0);
      }
    }

    // ---- epilogue: C/D layout col=lane&15, row=(lane>>4)*4+reg ----
    if(t<8){
      u16* yt=y+((size_t)t*NODES+d0)*HD;
#pragma unroll
      for(int tn=0;tn<4;tn++){
        int n=wn*64+tn*16+(lane&15);
#pragma unroll
        for(int tm=0;tm<2;tm++){
          int rbase=wm*32+tm*16+q*4;
#pragma unroll
          for(int r=0;r<4;r++)
            yt[(size_t)(rbase+r)*HD+n]=f2bf(acc[tm][tn][r]);
        }
      }
    } else {
      float* zt=z+(size_t)d0*HD;
#pragma unroll
      for(int tn=0;tn<4;tn++){
        int n=wn*64+tn*16+(lane&15);
#pragma unroll
        for(int tm=0;tm<2;tm++){
          int rbase=wm*32+tm*16+q*4;
#pragma unroll
          for(int r=0;r<4;r++)
            zt[(size_t)(rbase+r)*HD+n]=acc[tm][tn][r];
        }
      }
    }
  }
}

// ---------------- gather_combine: agg = (1/deg) * sum_e y[type][src]; out = relu(z+agg+b)
__global__ __launch_bounds__(256) void gather_combine(
    const u32* __restrict__ y, const float* __restrict__ z,
    const u32* __restrict__ adj, const u32* __restrict__ rp,
    const float* __restrict__ sb, const int* __restrict__ mask,
    u32* __restrict__ xh, u32* __restrict__ xl, float* __restrict__ outf, int last)
{
  const int wave=threadIdx.x>>6, lane=threadIdx.x&63;
  const int node=blockIdx.x*4+wave;
  const int beg=(int)rp[node], end=(int)rp[node+1];
  float a0=0.f, a1=0.f;
  int e=beg;
  for(; e+8<=end; e+=8){
    u32 qv[8], vv[8];
#pragma unroll
    for(int i=0;i<8;i++) qv[i]=adj[e+i];
#pragma unroll
    for(int i=0;i<8;i++) vv[i]=y[((size_t)(qv[i]>>16)*NODES+(qv[i]&0x7fffu))*64+lane];
#pragma unroll
    for(int i=0;i<8;i++){ a0+=bflo(vv[i]); a1+=bfhi(vv[i]); }
  }
  for(; e<end; ++e){
    u32 qq=adj[e];
    u32 v=y[((size_t)(qq>>16)*NODES+(qq&0x7fffu))*64+lane];
    a0+=bflo(v); a1+=bfhi(v);
  }
  float inv=1.f/fmaxf((float)(end-beg),1.f);
  float2 zz=*(const float2*)&z[(size_t)node*HD+2*lane];
  float2 bb=*(const float2*)&sb[2*lane];
  float v0=fmaxf(zz.x+a0*inv+bb.x,0.f);
  float v1=fmaxf(zz.y+a1*inv+bb.y,0.f);
  if(last){
    float mk=(float)mask[node];
    float2 o={v0*mk,v1*mk};
    *(float2*)&outf[(size_t)node*HD+2*lane]=o;
  } else {
    u16 h0=f2bf(v0), h1=f2bf(v1);
    u16 l0=f2bf(v0-bf2f(h0)), l1=f2bf(v1-bf2f(h1));
    xh[(size_t)node*64+lane]=(u32)h0|((u32)h1<<16);
    xl[(size_t)node*64+lane]=(u32)l0|((u32)l1<<16);
  }
}

extern "C" void kernel_launch(void* const* d_in, const int* in_sizes, int n_in,
                              void* d_out, int out_size, void* d_ws, size_t ws_size,
                              hipStream_t stream)
{
  (void)in_sizes; (void)n_in; (void)out_size; (void)ws_size;
  const int*   cid =(const int*)  d_in[0];
  const int*   kid =(const int*)  d_in[1];
  const int*   mask=(const int*)  d_in[2];
  const int*   ei  =(const int*)  d_in[3];
  const int*   et  =(const int*)  d_in[4];
  const float* cemb=(const float*)d_in[5];
  const float* kemb=(const float*)d_in[6];
  const float* pW  =(const float*)d_in[7];
  const float* pb  =(const float*)d_in[8];
  const float* sW  =(const float*)d_in[9];
  const float* sb  =(const float*)d_in[10];
  const float* rW  =(const float*)d_in[11];
  float* out=(float*)d_out;
  char*  ws =(char*)d_ws;

  u16* xh =(u16*)(ws+XH_OFF);
  u16* xl =(u16*)(ws+XL_OFF);
  u16* y  =(u16*)(ws+Y_OFF);
  float* z=(float*)(ws+Z_OFF);
  u32* adj =(u32*)(ws+ADJ_OFF);
  u32* rp  =(u32*)(ws+RP_OFF);
  u32* cur =(u32*)(ws+CUR_OFF);
  u32* bsum=(u32*)(ws+BSUM_OFF);
  u16* Bp  =(u16*)(ws+BP_OFF);
  const int* srcA=ei;
  const int* dstA=ei+NE;

  hipMemsetAsync(cur,0,NODES*sizeof(u32),stream);
  prep_w<<<1152,256,0,stream>>>(rW,sW,Bp);
  embed_gemm<<<NODES/64,256,0,stream>>>(cid,kid,cemb,kemb,pW,pb,xh,xl);
  count_deg<<<NE/256,256,0,stream>>>(dstA,cur);
  scan1<<<NODES/256,256,0,stream>>>(cur,rp,bsum);
  scan2<<<1,128,0,stream>>>(bsum,rp);
  scan3<<<NODES/256,256,0,stream>>>(rp,bsum);
  hipMemsetAsync(cur,0,NODES*sizeof(u32),stream);
  scatter_edges<<<NE/256,256,0,stream>>>(srcA,dstA,et,rp,cur,adj);

  // layer 0
  gemm_y<<<dim3(NODES/64,3),256,0,stream>>>(xh,xl,Bp,y,z);
  gather_combine<<<NODES/4,256,0,stream>>>((const u32*)y,z,adj,rp,sb,mask,(u32*)xh,(u32*)xl,out,0);
  // layer 1
  gemm_y<<<dim3(NODES/64,3),256,0,stream>>>(xh,xl,Bp+BP_LAYER,y,z);
  gather_combine<<<NODES/4,256,0,stream>>>((const u32*)y,z,adj,rp,sb+HD,mask,(u32*)xh,(u32*)xl,out,1);
}

// Round 7
// 371.910 us; speedup vs baseline: 1.5302x; 1.5302x over previous
//
#include <hip/hip_runtime.h>
#include <hip/hip_bf16.h>

#define NODES 32768
#define HD 128
#define NE 524288
#define NR 8

typedef unsigned int u32;
typedef unsigned short u16;
typedef __attribute__((ext_vector_type(8))) short bf16x8;
typedef __attribute__((ext_vector_type(4))) float f32x4;

// ---- ws byte offsets ----
#define XH_OFF   (0u)                      // bf16 hi, 8 MB (reused both layers)
#define XL_OFF   (8u<<20)                  // bf16 lo, 8 MB
#define Y_OFF    (16u<<20)                 // bf16 y[8][NODES][128], 64 MB
#define Z_OFF    (80u<<20)                 // fp32 z[NODES][128], 16 MB
#define ADJ_OFF  (96u<<20)                 // u32 x NE
#define RP_OFF   (98u<<20)                 // u32 x (NODES+1)
#define CUR_OFF  ((98u<<20)+(256u<<10))    // u32 x NODES
#define BSUM_OFF ((98u<<20)+(512u<<10))    // u32 x 128
#define BP_OFF   ((98u<<20)+(640u<<10))    // packed weights bf16: 2 layers x 9 tiles x 2 segs x 16384

#define BP_LAYER 294912                    // 9*2*16384

__device__ __forceinline__ float bflo(u32 u){ union{u32 i;float f;}c; c.i=u<<16; return c.f; }
__device__ __forceinline__ float bfhi(u32 u){ union{u32 i;float f;}c; c.i=u&0xffff0000u; return c.f; }
__device__ __forceinline__ u16 f2bf(float f){
  u32 u=__float_as_uint(f);
  u32 r=u + 0x7fffu + ((u>>16)&1u);
  return (u16)(r>>16);
}
__device__ __forceinline__ float bf2f(u16 h){ return __uint_as_float(((u32)h)<<16); }

// ---------------- embed + projection GEMM (fp32 vector) ----------------
__device__ __forceinline__ void fma64(const float* At, const float* Wt,
                                      int mq, int gq, float acc[8][4])
{
#pragma unroll 8
  for(int kk=0;kk<64;kk++){
    const float4 a0=*(const float4*)&At[kk*68+mq*8];
    const float4 a1=*(const float4*)&At[kk*68+mq*8+4];
    const float4 w =*(const float4*)&Wt[kk*132+gq*4];
    float av[8]={a0.x,a0.y,a0.z,a0.w,a1.x,a1.y,a1.z,a1.w};
#pragma unroll
    for(int i=0;i<8;i++){
      acc[i][0]=fmaf(av[i],w.x,acc[i][0]);
      acc[i][1]=fmaf(av[i],w.y,acc[i][1]);
      acc[i][2]=fmaf(av[i],w.z,acc[i][2]);
      acc[i][3]=fmaf(av[i],w.w,acc[i][3]);
    }
  }
}

__global__ __launch_bounds__(256) void embed_gemm(
    const int* __restrict__ cid, const int* __restrict__ kid,
    const float* __restrict__ cemb, const float* __restrict__ kemb,
    const float* __restrict__ pW, const float* __restrict__ pb,
    u16* __restrict__ xh, u16* __restrict__ xl)
{
  __shared__ float At[64*68];
  __shared__ float Wt[64*132];
  const int tid=threadIdx.x;
  const int d0=blockIdx.x*64;
  const int mq=tid>>5, gq=tid&31;
  float acc[8][4];
#pragma unroll
  for(int i=0;i<8;i++){ acc[i][0]=0.f; acc[i][1]=0.f; acc[i][2]=0.f; acc[i][3]=0.f; }

  for(int c=0;c<2;c++){
    const int h0=c*64;
    __syncthreads();
    { int m=tid>>2; int hh=(tid&3)*16;
      int ci=cid[d0+m], ki=kid[d0+m];
      const float* cp=cemb+(size_t)ci*HD+h0+hh;
      const float* kp=kemb+(size_t)ki*HD+h0+hh;
      float* ap=&At[hh*68+m];
#pragma unroll
      for(int j=0;j<16;j+=4){
        float4 a=*(const float4*)(cp+j);
        float4 b=*(const float4*)(kp+j);
        ap[(j+0)*68]=a.x+b.x; ap[(j+1)*68]=a.y+b.y;
        ap[(j+2)*68]=a.z+b.z; ap[(j+3)*68]=a.w+b.w;
      }
    }
    { int g=tid>>1; int hh=(tid&1)*32;
      const float* wp=pW+(size_t)g*HD+h0+hh;
      float* wl=&Wt[hh*132+g];
#pragma unroll
      for(int j=0;j<32;j+=4){
        float4 w=*(const float4*)(wp+j);
        wl[(j+0)*132]=w.x; wl[(j+1)*132]=w.y; wl[(j+2)*132]=w.z; wl[(j+3)*132]=w.w;
      }
    }
    __syncthreads();
    fma64(At,Wt,mq,gq,acc);
  }
  const float4 bias=*(const float4*)&pb[gq*4];
#pragma unroll
  for(int i=0;i<8;i++){
    int m=d0+mq*8+i;
    float v[4]={acc[i][0]+bias.x,acc[i][1]+bias.y,acc[i][2]+bias.z,acc[i][3]+bias.w};
    u16 hb[4], lb[4];
#pragma unroll
    for(int j=0;j<4;j++){ hb[j]=f2bf(v[j]); lb[j]=f2bf(v[j]-bf2f(hb[j])); }
    uint2 hv={(u32)hb[0]|((u32)hb[1]<<16),(u32)hb[2]|((u32)hb[3]<<16)};
    uint2 lv={(u32)lb[0]|((u32)lb[1]<<16),(u32)lb[2]|((u32)lb[3]<<16)};
    *(uint2*)&xh[(size_t)m*HD+gq*4]=hv;
    *(uint2*)&xl[(size_t)m*HD+gq*4]=lv;
  }
}

// ---------------- weight prep: per layer, 9 n-tiles (8 relations + self), hi/lo segs,
// MFMA-fragment-contiguous: k = ks32*32 + q*8 + j -> (ks32*128+n)*32 + q*8 + j
__global__ void prep_w(const float* __restrict__ rW, const float* __restrict__ sW,
                       u16* __restrict__ Bp)
{
  int idx=blockIdx.x*256+threadIdx.x;           // 2 * 9 * 16384 = 294912 total
  int l=idx/147456;
  int rem=idx%147456;
  int t=rem>>14;
  int kn=rem&16383;
  int k=kn>>7, n=kn&127;
  float w;
  if(t<8) w=rW[(((size_t)l*NR+t)*HD+n)*HD+k];
  else    w=sW[((size_t)l*HD+n)*HD+k];
  u16* base=Bp+(size_t)l*BP_LAYER+(size_t)t*32768;
  int ks=k>>5, q=(k>>3)&3, j=k&7;
  size_t off=((size_t)ks*128+n)*32+q*8+j;
  u16 hb=f2bf(w);
  u16 lb=f2bf(w-bf2f(hb));
  base[off]=hb;
  base[off+16384]=lb;
}

// ---------------- CSR build ----------------
__global__ void count_deg(const int* __restrict__ dst, u32* __restrict__ cnt){
  int e=blockIdx.x*256+threadIdx.x;
  atomicAdd(&cnt[dst[e]],1u);
}

__global__ void scan1(const u32* __restrict__ cnt, u32* __restrict__ rp, u32* __restrict__ bsum){
  __shared__ u32 sh[256];
  int t=threadIdx.x; int base=blockIdx.x*256;
  u32 v=cnt[base+t]; sh[t]=v; __syncthreads();
  for(int off=1;off<256;off<<=1){
    u32 tv=(t>=off)?sh[t-off]:0u; __syncthreads();
    sh[t]+=tv; __syncthreads();
  }
  rp[base+t]=sh[t]-v;
  if(t==255) bsum[blockIdx.x]=sh[255];
}

__global__ void scan2(u32* __restrict__ bsum, u32* __restrict__ rp){
  __shared__ u32 sh[128];
  int t=threadIdx.x;
  u32 v=bsum[t]; sh[t]=v; __syncthreads();
  for(int off=1;off<128;off<<=1){
    u32 tv=(t>=off)?sh[t-off]:0u; __syncthreads();
    sh[t]+=tv; __syncthreads();
  }
  bsum[t]=sh[t]-v;
  if(t==0) rp[NODES]=NE;
}

__global__ void scan3(u32* __restrict__ rp, const u32* __restrict__ bsum){
  int i=blockIdx.x*256+threadIdx.x;
  rp[i]+=bsum[blockIdx.x];
}

__global__ void scatter_edges(const int* __restrict__ src, const int* __restrict__ dst,
                              const int* __restrict__ et, const u32* __restrict__ rp,
                              u32* __restrict__ cur, u32* __restrict__ adj){
  int e=blockIdx.x*256+threadIdx.x;
  int d=dst[e];
  u32 pos=atomicAdd(&cur[d],1u);
  adj[rp[d]+pos]=(u32)src[e] | ((u32)et[e]<<16);
}

// ---------------- gemm_y: 128x128 tile, one t per block, NO LDS / NO BARRIERS ----------
// y[t] = x @ W_t^T (t<8, bf16 out), z = x @ selfW^T (t==8, fp32 out)
// grid (NODES/128, 9); waves 2x2. A fragments (16B contiguous along k) loaded
// directly from global: frag(m, ks) = x[row m][ks*32 + q*8 .. +8].
__global__ __launch_bounds__(256,3) void gemm_y(
    const u16* __restrict__ xhi, const u16* __restrict__ xlo,
    const u16* __restrict__ Bt, u16* __restrict__ y, float* __restrict__ z)
{
  const int tid=threadIdx.x;
  const int wave=tid>>6, lane=tid&63;
  const int wm=wave>>1, wn=wave&1;
  const int q=lane>>4;
  const int d0=blockIdx.x*128;
  const int t=blockIdx.y;
  const u16* Btile=Bt+(size_t)t*32768;

  f32x4 acc[4][4];
#pragma unroll
  for(int a=0;a<4;a++)
#pragma unroll
    for(int b=0;b<4;b++) acc[a][b]=(f32x4){0.f,0.f,0.f,0.f};

  const int mrow = d0 + wm*64 + (lane&15);   // + tm*16
  const int koff = q*8;                      // + ks*32

  // ---- part 0: xhi @ {Whi, Wlo} ----
#pragma unroll
  for(int ks=0;ks<4;ks++){
    bf16x8 ahi[4];
#pragma unroll
    for(int tm=0;tm<4;tm++)
      ahi[tm]=*(const bf16x8*)&xhi[(size_t)(mrow+tm*16)*HD + ks*32 + koff];
#pragma unroll
    for(int s=0;s<2;s++){
      const u16* Bb=Btile+s*16384;
#pragma unroll
      for(int tn=0;tn<4;tn++){
        int n=wn*64+tn*16+(lane&15);
        bf16x8 bfr=*(const bf16x8*)&Bb[((size_t)ks*128+n)*32+koff];
#pragma unroll
        for(int tm=0;tm<4;tm++)
          acc[tm][tn]=__builtin_amdgcn_mfma_f32_16x16x32_bf16(ahi[tm],bfr,acc[tm][tn],0,0,0);
      }
    }
  }

  // ---- part 1: xlo @ Whi ----
#pragma unroll
  for(int ks=0;ks<4;ks++){
    bf16x8 alo[4];
#pragma unroll
    for(int tm=0;tm<4;tm++)
      alo[tm]=*(const bf16x8*)&xlo[(size_t)(mrow+tm*16)*HD + ks*32 + koff];
#pragma unroll
    for(int tn=0;tn<4;tn++){
      int n=wn*64+tn*16+(lane&15);
      bf16x8 bfr=*(const bf16x8*)&Btile[((size_t)ks*128+n)*32+koff];
#pragma unroll
      for(int tm=0;tm<4;tm++)
        acc[tm][tn]=__builtin_amdgcn_mfma_f32_16x16x32_bf16(alo[tm],bfr,acc[tm][tn],0,0,0);
    }
  }

  // ---- epilogue: C/D layout col=lane&15, row=(lane>>4)*4+reg ----
  if(t<8){
    u16* yt=y+((size_t)t*NODES+d0)*HD;
#pragma unroll
    for(int tn=0;tn<4;tn++){
      int n=wn*64+tn*16+(lane&15);
#pragma unroll
      for(int tm=0;tm<4;tm++){
        int rbase=wm*64+tm*16+q*4;
#pragma unroll
        for(int r=0;r<4;r++)
          yt[(size_t)(rbase+r)*HD+n]=f2bf(acc[tm][tn][r]);
      }
    }
  } else {
    float* zt=z+(size_t)d0*HD;
#pragma unroll
    for(int tn=0;tn<4;tn++){
      int n=wn*64+tn*16+(lane&15);
#pragma unroll
      for(int tm=0;tm<4;tm++){
        int rbase=wm*64+tm*16+q*4;
#pragma unroll
        for(int r=0;r<4;r++)
          zt[(size_t)(rbase+r)*HD+n]=acc[tm][tn][r];
      }
    }
  }
}

// ---------------- gather_combine: agg = (1/deg) * sum_e y[type][src]; out = relu(z+agg+b)
__global__ __launch_bounds__(256) void gather_combine(
    const u32* __restrict__ y, const float* __restrict__ z,
    const u32* __restrict__ adj, const u32* __restrict__ rp,
    const float* __restrict__ sb, const int* __restrict__ mask,
    u32* __restrict__ xh, u32* __restrict__ xl, float* __restrict__ outf, int last)
{
  const int wave=threadIdx.x>>6, lane=threadIdx.x&63;
  const int node=blockIdx.x*4+wave;
  const int beg=(int)rp[node], end=(int)rp[node+1];
  float a0=0.f, a1=0.f;
  int e=beg;
  for(; e+8<=end; e+=8){
    u32 qv[8], vv[8];
#pragma unroll
    for(int i=0;i<8;i++) qv[i]=adj[e+i];
#pragma unroll
    for(int i=0;i<8;i++) vv[i]=y[((size_t)(qv[i]>>16)*NODES+(qv[i]&0x7fffu))*64+lane];
#pragma unroll
    for(int i=0;i<8;i++){ a0+=bflo(vv[i]); a1+=bfhi(vv[i]); }
  }
  for(; e<end; ++e){
    u32 qq=adj[e];
    u32 v=y[((size_t)(qq>>16)*NODES+(qq&0x7fffu))*64+lane];
    a0+=bflo(v); a1+=bfhi(v);
  }
  float inv=1.f/fmaxf((float)(end-beg),1.f);
  float2 zz=*(const float2*)&z[(size_t)node*HD+2*lane];
  float2 bb=*(const float2*)&sb[2*lane];
  float v0=fmaxf(zz.x+a0*inv+bb.x,0.f);
  float v1=fmaxf(zz.y+a1*inv+bb.y,0.f);
  if(last){
    float mk=(float)mask[node];
    float2 o={v0*mk,v1*mk};
    *(float2*)&outf[(size_t)node*HD+2*lane]=o;
  } else {
    u16 h0=f2bf(v0), h1=f2bf(v1);
    u16 l0=f2bf(v0-bf2f(h0)), l1=f2bf(v1-bf2f(h1));
    xh[(size_t)node*64+lane]=(u32)h0|((u32)h1<<16);
    xl[(size_t)node*64+lane]=(u32)l0|((u32)l1<<16);
  }
}

extern "C" void kernel_launch(void* const* d_in, const int* in_sizes, int n_in,
                              void* d_out, int out_size, void* d_ws, size_t ws_size,
                              hipStream_t stream)
{
  (void)in_sizes; (void)n_in; (void)out_size; (void)ws_size;
  const int*   cid =(const int*)  d_in[0];
  const int*   kid =(const int*)  d_in[1];
  const int*   mask=(const int*)  d_in[2];
  const int*   ei  =(const int*)  d_in[3];
  const int*   et  =(const int*)  d_in[4];
  const float* cemb=(const float*)d_in[5];
  const float* kemb=(const float*)d_in[6];
  const float* pW  =(const float*)d_in[7];
  const float* pb  =(const float*)d_in[8];
  const float* sW  =(const float*)d_in[9];
  const float* sb  =(const float*)d_in[10];
  const float* rW  =(const float*)d_in[11];
  float* out=(float*)d_out;
  char*  ws =(char*)d_ws;

  u16* xh =(u16*)(ws+XH_OFF);
  u16* xl =(u16*)(ws+XL_OFF);
  u16* y  =(u16*)(ws+Y_OFF);
  float* z=(float*)(ws+Z_OFF);
  u32* adj =(u32*)(ws+ADJ_OFF);
  u32* rp  =(u32*)(ws+RP_OFF);
  u32* cur =(u32*)(ws+CUR_OFF);
  u32* bsum=(u32*)(ws+BSUM_OFF);
  u16* Bp  =(u16*)(ws+BP_OFF);
  const int* srcA=ei;
  const int* dstA=ei+NE;

  hipMemsetAsync(cur,0,NODES*sizeof(u32),stream);
  prep_w<<<1152,256,0,stream>>>(rW,sW,Bp);
  embed_gemm<<<NODES/64,256,0,stream>>>(cid,kid,cemb,kemb,pW,pb,xh,xl);
  count_deg<<<NE/256,256,0,stream>>>(dstA,cur);
  scan1<<<NODES/256,256,0,stream>>>(cur,rp,bsum);
  scan2<<<1,128,0,stream>>>(bsum,rp);
  scan3<<<NODES/256,256,0,stream>>>(rp,bsum);
  hipMemsetAsync(cur,0,NODES*sizeof(u32),stream);
  scatter_edges<<<NE/256,256,0,stream>>>(srcA,dstA,et,rp,cur,adj);

  // layer 0
  gemm_y<<<dim3(NODES/128,9),256,0,stream>>>(xh,xl,Bp,y,z);
  gather_combine<<<NODES/4,256,0,stream>>>((const u32*)y,z,adj,rp,sb,mask,(u32*)xh,(u32*)xl,out,0);
  // layer 1
  gemm_y<<<dim3(NODES/128,9),256,0,stream>>>(xh,xl,Bp+BP_LAYER,y,z);
  gather_combine<<<NODES/4,256,0,stream>>>((const u32*)y,z,adj,rp,sb+HD,mask,(u32*)xh,(u32*)xl,out,1);
}

// Round 8
// 351.820 us; speedup vs baseline: 1.6176x; 1.0571x over previous
//
#include <hip/hip_runtime.h>
#include <hip/hip_bf16.h>

#define NODES 32768
#define HD 128
#define NE 524288
#define NR 8

typedef unsigned int u32;
typedef unsigned short u16;
typedef __attribute__((ext_vector_type(8))) short bf16x8;
typedef __attribute__((ext_vector_type(4))) float f32x4;

// ---- ws byte offsets ----
#define XH_OFF   (0u)                      // bf16 hi, 8 MB (reused both layers)
#define XL_OFF   (8u<<20)                  // bf16 lo, 8 MB
#define Y_OFF    (16u<<20)                 // bf16 y[8][NODES][128], 64 MB
#define Z_OFF    (80u<<20)                 // fp32 z[NODES][128], 16 MB
#define ADJ_OFF  (96u<<20)                 // u32 x NE
#define RP_OFF   (98u<<20)                 // u32 x (NODES+1)
#define CUR_OFF  ((98u<<20)+(256u<<10))    // u32 x NODES
#define BSUM_OFF ((98u<<20)+(512u<<10))    // u32 x 128
#define BP_OFF   ((98u<<20)+(640u<<10))    // packed weights bf16: 2 layers x 9 tiles x 2 segs x 16384

#define BP_LAYER 294912                    // 9*2*16384

__device__ __forceinline__ float bflo(u32 u){ union{u32 i;float f;}c; c.i=u<<16; return c.f; }
__device__ __forceinline__ float bfhi(u32 u){ union{u32 i;float f;}c; c.i=u&0xffff0000u; return c.f; }
__device__ __forceinline__ u16 f2bf(float f){
  u32 u=__float_as_uint(f);
  u32 r=u + 0x7fffu + ((u>>16)&1u);
  return (u16)(r>>16);
}
__device__ __forceinline__ float bf2f(u16 h){ return __uint_as_float(((u32)h)<<16); }

__device__ __forceinline__ void gl_lds16(const void* g, void* l){
  __builtin_amdgcn_global_load_lds((const __attribute__((address_space(1))) u32*)g,
                                   (__attribute__((address_space(3))) u32*)l, 16, 0, 0);
}

// ---------------- embed + projection GEMM (fp32 vector) ----------------
__device__ __forceinline__ void fma64(const float* At, const float* Wt,
                                      int mq, int gq, float acc[8][4])
{
#pragma unroll 8
  for(int kk=0;kk<64;kk++){
    const float4 a0=*(const float4*)&At[kk*68+mq*8];
    const float4 a1=*(const float4*)&At[kk*68+mq*8+4];
    const float4 w =*(const float4*)&Wt[kk*132+gq*4];
    float av[8]={a0.x,a0.y,a0.z,a0.w,a1.x,a1.y,a1.z,a1.w};
#pragma unroll
    for(int i=0;i<8;i++){
      acc[i][0]=fmaf(av[i],w.x,acc[i][0]);
      acc[i][1]=fmaf(av[i],w.y,acc[i][1]);
      acc[i][2]=fmaf(av[i],w.z,acc[i][2]);
      acc[i][3]=fmaf(av[i],w.w,acc[i][3]);
    }
  }
}

__global__ __launch_bounds__(256) void embed_gemm(
    const int* __restrict__ cid, const int* __restrict__ kid,
    const float* __restrict__ cemb, const float* __restrict__ kemb,
    const float* __restrict__ pW, const float* __restrict__ pb,
    u16* __restrict__ xh, u16* __restrict__ xl)
{
  __shared__ float At[64*68];
  __shared__ float Wt[64*132];
  const int tid=threadIdx.x;
  const int d0=blockIdx.x*64;
  const int mq=tid>>5, gq=tid&31;
  float acc[8][4];
#pragma unroll
  for(int i=0;i<8;i++){ acc[i][0]=0.f; acc[i][1]=0.f; acc[i][2]=0.f; acc[i][3]=0.f; }

  for(int c=0;c<2;c++){
    const int h0=c*64;
    __syncthreads();
    { int m=tid>>2; int hh=(tid&3)*16;
      int ci=cid[d0+m], ki=kid[d0+m];
      const float* cp=cemb+(size_t)ci*HD+h0+hh;
      const float* kp=kemb+(size_t)ki*HD+h0+hh;
      float* ap=&At[hh*68+m];
#pragma unroll
      for(int j=0;j<16;j+=4){
        float4 a=*(const float4*)(cp+j);
        float4 b=*(const float4*)(kp+j);
        ap[(j+0)*68]=a.x+b.x; ap[(j+1)*68]=a.y+b.y;
        ap[(j+2)*68]=a.z+b.z; ap[(j+3)*68]=a.w+b.w;
      }
    }
    { int g=tid>>1; int hh=(tid&1)*32;
      const float* wp=pW+(size_t)g*HD+h0+hh;
      float* wl=&Wt[hh*132+g];
#pragma unroll
      for(int j=0;j<32;j+=4){
        float4 w=*(const float4*)(wp+j);
        wl[(j+0)*132]=w.x; wl[(j+1)*132]=w.y; wl[(j+2)*132]=w.z; wl[(j+3)*132]=w.w;
      }
    }
    __syncthreads();
    fma64(At,Wt,mq,gq,acc);
  }
  const float4 bias=*(const float4*)&pb[gq*4];
#pragma unroll
  for(int i=0;i<8;i++){
    int m=d0+mq*8+i;
    float v[4]={acc[i][0]+bias.x,acc[i][1]+bias.y,acc[i][2]+bias.z,acc[i][3]+bias.w};
    u16 hb[4], lb[4];
#pragma unroll
    for(int j=0;j<4;j++){ hb[j]=f2bf(v[j]); lb[j]=f2bf(v[j]-bf2f(hb[j])); }
    uint2 hv={(u32)hb[0]|((u32)hb[1]<<16),(u32)hb[2]|((u32)hb[3]<<16)};
    uint2 lv={(u32)lb[0]|((u32)lb[1]<<16),(u32)lb[2]|((u32)lb[3]<<16)};
    *(uint2*)&xh[(size_t)m*HD+gq*4]=hv;
    *(uint2*)&xl[(size_t)m*HD+gq*4]=lv;
  }
}

// ---------------- weight prep: per layer, 9 n-tiles (8 relations + self), hi/lo segs,
// MFMA-fragment-contiguous: k = ks32*32 + q*8 + j -> (ks32*128+n)*32 + q*8 + j
__global__ void prep_w(const float* __restrict__ rW, const float* __restrict__ sW,
                       u16* __restrict__ Bp)
{
  int idx=blockIdx.x*256+threadIdx.x;           // 2 * 9 * 16384 = 294912 total
  int l=idx/147456;
  int rem=idx%147456;
  int t=rem>>14;
  int kn=rem&16383;
  int k=kn>>7, n=kn&127;
  float w;
  if(t<8) w=rW[(((size_t)l*NR+t)*HD+n)*HD+k];
  else    w=sW[((size_t)l*HD+n)*HD+k];
  u16* base=Bp+(size_t)l*BP_LAYER+(size_t)t*32768;
  int ks=k>>5, q=(k>>3)&3, j=k&7;
  size_t off=((size_t)ks*128+n)*32+q*8+j;
  u16 hb=f2bf(w);
  u16 lb=f2bf(w-bf2f(hb));
  base[off]=hb;
  base[off+16384]=lb;
}

// ---------------- CSR build ----------------
__global__ void count_deg(const int* __restrict__ dst, u32* __restrict__ cnt){
  int e=blockIdx.x*256+threadIdx.x;
  atomicAdd(&cnt[dst[e]],1u);
}

__global__ void scan1(const u32* __restrict__ cnt, u32* __restrict__ rp, u32* __restrict__ bsum){
  __shared__ u32 sh[256];
  int t=threadIdx.x; int base=blockIdx.x*256;
  u32 v=cnt[base+t]; sh[t]=v; __syncthreads();
  for(int off=1;off<256;off<<=1){
    u32 tv=(t>=off)?sh[t-off]:0u; __syncthreads();
    sh[t]+=tv; __syncthreads();
  }
  rp[base+t]=sh[t]-v;
  if(t==255) bsum[blockIdx.x]=sh[255];
}

__global__ void scan2(u32* __restrict__ bsum, u32* __restrict__ rp){
  __shared__ u32 sh[128];
  int t=threadIdx.x;
  u32 v=bsum[t]; sh[t]=v; __syncthreads();
  for(int off=1;off<128;off<<=1){
    u32 tv=(t>=off)?sh[t-off]:0u; __syncthreads();
    sh[t]+=tv; __syncthreads();
  }
  bsum[t]=sh[t]-v;
  if(t==0) rp[NODES]=NE;
}

__global__ void scan3(u32* __restrict__ rp, const u32* __restrict__ bsum){
  int i=blockIdx.x*256+threadIdx.x;
  rp[i]+=bsum[blockIdx.x];
}

__global__ void scatter_edges(const int* __restrict__ src, const int* __restrict__ dst,
                              const int* __restrict__ et, const u32* __restrict__ rp,
                              u32* __restrict__ cur, u32* __restrict__ adj){
  int e=blockIdx.x*256+threadIdx.x;
  int d=dst[e];
  u32 pos=atomicAdd(&cur[d],1u);
  adj[rp[d]+pos]=(u32)src[e] | ((u32)et[e]<<16);
}

// ---------------- gemm_y: 64-row tile, ONE t per block, ONE barrier ----------------
// y[t] = x @ W_t^T (t<8, bf16 out), z = x @ selfW^T (t==8, fp32 out)
// grid (NODES/64, 9); 4 waves: wm=wave>>1 (2 row-halves of 32), wn=wave&1 (2 col-halves)
// LDS: xhi 16 KB + xlo 16 KB staged together -> single __syncthreads in the kernel
__global__ __launch_bounds__(256,4) void gemm_y(
    const u16* __restrict__ xhi, const u16* __restrict__ xlo,
    const u16* __restrict__ Bt, u16* __restrict__ y, float* __restrict__ z)
{
  __shared__ u16 Atile[2][64*128];   // [0]=xhi, [1]=xlo; row=256B, 16B-chunk XOR-16 swizzle
  const int tid=threadIdx.x;
  const int wave=tid>>6, lane=tid&63;
  const int wm=wave>>1, wn=wave&1;
  const int q=lane>>4;
  const int d0=blockIdx.x*64;
  const int t=blockIdx.y;
  const u16* Btile=Bt+(size_t)t*32768;

  const int st_c  = lane&15;        // dest 16B chunk within row
  const int st_rin= lane>>4;        // row within 4-row issue

  // ---- stage xhi + xlo (each wave: rows wave*16..+16 of both), one barrier ----
#pragma unroll
  for(int i=0;i<4;i++){
    int rbase=wave*16+i*4;
    int r=rbase+st_rin;
    int g=st_c ^ (r&15);
    gl_lds16(xhi+(size_t)(d0+r)*HD+g*8, &Atile[0][rbase*128]);
  }
#pragma unroll
  for(int i=0;i<4;i++){
    int rbase=wave*16+i*4;
    int r=rbase+st_rin;
    int g=st_c ^ (r&15);
    gl_lds16(xlo+(size_t)(d0+r)*HD+g*8, &Atile[1][rbase*128]);
  }
  __syncthreads();

  f32x4 acc[2][4];
#pragma unroll
  for(int a=0;a<2;a++)
#pragma unroll
    for(int b=0;b<4;b++) acc[a][b]=(f32x4){0.f,0.f,0.f,0.f};

  // ---- part 0: xhi @ {Whi, Wlo} ----
#pragma unroll
  for(int ks=0;ks<4;ks++){
    bf16x8 ah[2];
#pragma unroll
    for(int tm=0;tm<2;tm++){
      int m=wm*32+tm*16+(lane&15);
      ah[tm]=*(const bf16x8*)&Atile[0][m*128+(((ks*4)+q)^(m&15))*8];
    }
#pragma unroll
    for(int s=0;s<2;s++){
      const u16* Bb=Btile+s*16384;
#pragma unroll
      for(int tn=0;tn<4;tn++){
        int n=wn*64+tn*16+(lane&15);
        bf16x8 bfr=*(const bf16x8*)&Bb[((size_t)ks*128+n)*32+q*8];
#pragma unroll
        for(int tm=0;tm<2;tm++)
          acc[tm][tn]=__builtin_amdgcn_mfma_f32_16x16x32_bf16(ah[tm],bfr,acc[tm][tn],0,0,0);
      }
    }
  }

  // ---- part 1: xlo @ Whi ----
#pragma unroll
  for(int ks=0;ks<4;ks++){
    bf16x8 al[2];
#pragma unroll
    for(int tm=0;tm<2;tm++){
      int m=wm*32+tm*16+(lane&15);
      al[tm]=*(const bf16x8*)&Atile[1][m*128+(((ks*4)+q)^(m&15))*8];
    }
#pragma unroll
    for(int tn=0;tn<4;tn++){
      int n=wn*64+tn*16+(lane&15);
      bf16x8 bfr=*(const bf16x8*)&Btile[((size_t)ks*128+n)*32+q*8];
#pragma unroll
      for(int tm=0;tm<2;tm++)
        acc[tm][tn]=__builtin_amdgcn_mfma_f32_16x16x32_bf16(al[tm],bfr,acc[tm][tn],0,0,0);
    }
  }

  // ---- epilogue: C/D layout col=lane&15, row=(lane>>4)*4+reg ----
  if(t<8){
    u16* yt=y+((size_t)t*NODES+d0)*HD;
#pragma unroll
    for(int tn=0;tn<4;tn++){
      int n=wn*64+tn*16+(lane&15);
#pragma unroll
      for(int tm=0;tm<2;tm++){
        int rbase=wm*32+tm*16+q*4;
#pragma unroll
        for(int r=0;r<4;r++)
          yt[(size_t)(rbase+r)*HD+n]=f2bf(acc[tm][tn][r]);
      }
    }
  } else {
    float* zt=z+(size_t)d0*HD;
#pragma unroll
    for(int tn=0;tn<4;tn++){
      int n=wn*64+tn*16+(lane&15);
#pragma unroll
      for(int tm=0;tm<2;tm++){
        int rbase=wm*32+tm*16+q*4;
#pragma unroll
        for(int r=0;r<4;r++)
          zt[(size_t)(rbase+r)*HD+n]=acc[tm][tn][r];
      }
    }
  }
}

// ---------------- gather_combine: agg = (1/deg) * sum_e y[type][src]; out = relu(z+agg+b)
// adj entries for a node are read ONCE per 64 edges (coalesced, one lane each) and
// broadcast via __shfl, so y-loads pipeline without an interleaved adj dependency.
__global__ __launch_bounds__(256) void gather_combine(
    const u32* __restrict__ y, const float* __restrict__ z,
    const u32* __restrict__ adj, const u32* __restrict__ rp,
    const float* __restrict__ sb, const int* __restrict__ mask,
    u32* __restrict__ xh, u32* __restrict__ xl, float* __restrict__ outf, int last)
{
  const int wave=threadIdx.x>>6, lane=threadIdx.x&63;
  const int node=blockIdx.x*4+wave;
  const int beg=(int)rp[node], end=(int)rp[node+1];
  float a0=0.f, a1=0.f;

  for(int base=beg; base<end; base+=64){
    int nk=end-base; if(nk>64) nk=64;
    u32 adjv = (lane<nk) ? adj[base+lane] : 0u;
    int i=0;
    for(; i+8<=nk; i+=8){
      u32 vv[8];
#pragma unroll
      for(int j=0;j<8;j++){
        u32 qq=(u32)__shfl((int)adjv, i+j);
        vv[j]=y[(size_t)(qq>>16)*(NODES*64)+(size_t)(qq&0xffffu)*64+lane];
      }
#pragma unroll
      for(int j=0;j<8;j++){ a0+=bflo(vv[j]); a1+=bfhi(vv[j]); }
    }
    for(; i<nk; ++i){
      u32 qq=(u32)__shfl((int)adjv, i);
      u32 v=y[(size_t)(qq>>16)*(NODES*64)+(size_t)(qq&0xffffu)*64+lane];
      a0+=bflo(v); a1+=bfhi(v);
    }
  }

  float inv=1.f/fmaxf((float)(end-beg),1.f);
  float2 zz=*(const float2*)&z[(size_t)node*HD+2*lane];
  float2 bb=*(const float2*)&sb[2*lane];
  float v0=fmaxf(zz.x+a0*inv+bb.x,0.f);
  float v1=fmaxf(zz.y+a1*inv+bb.y,0.f);
  if(last){
    float mk=(float)mask[node];
    float2 o={v0*mk,v1*mk};
    *(float2*)&outf[(size_t)node*HD+2*lane]=o;
  } else {
    u16 h0=f2bf(v0), h1=f2bf(v1);
    u16 l0=f2bf(v0-bf2f(h0)), l1=f2bf(v1-bf2f(h1));
    xh[(size_t)node*64+lane]=(u32)h0|((u32)h1<<16);
    xl[(size_t)node*64+lane]=(u32)l0|((u32)l1<<16);
  }
}

extern "C" void kernel_launch(void* const* d_in, const int* in_sizes, int n_in,
                              void* d_out, int out_size, void* d_ws, size_t ws_size,
                              hipStream_t stream)
{
  (void)in_sizes; (void)n_in; (void)out_size; (void)ws_size;
  const int*   cid =(const int*)  d_in[0];
  const int*   kid =(const int*)  d_in[1];
  const int*   mask=(const int*)  d_in[2];
  const int*   ei  =(const int*)  d_in[3];
  const int*   et  =(const int*)  d_in[4];
  const float* cemb=(const float*)d_in[5];
  const float* kemb=(const float*)d_in[6];
  const float* pW  =(const float*)d_in[7];
  const float* pb  =(const float*)d_in[8];
  const float* sW  =(const float*)d_in[9];
  const float* sb  =(const float*)d_in[10];
  const float* rW  =(const float*)d_in[11];
  float* out=(float*)d_out;
  char*  ws =(char*)d_ws;

  u16* xh =(u16*)(ws+XH_OFF);
  u16* xl =(u16*)(ws+XL_OFF);
  u16* y  =(u16*)(ws+Y_OFF);
  float* z=(float*)(ws+Z_OFF);
  u32* adj =(u32*)(ws+ADJ_OFF);
  u32* rp  =(u32*)(ws+RP_OFF);
  u32* cur =(u32*)(ws+CUR_OFF);
  u32* bsum=(u32*)(ws+BSUM_OFF);
  u16* Bp  =(u16*)(ws+BP_OFF);
  const int* srcA=ei;
  const int* dstA=ei+NE;

  hipMemsetAsync(cur,0,NODES*sizeof(u32),stream);
  prep_w<<<1152,256,0,stream>>>(rW,sW,Bp);
  embed_gemm<<<NODES/64,256,0,stream>>>(cid,kid,cemb,kemb,pW,pb,xh,xl);
  count_deg<<<NE/256,256,0,stream>>>(dstA,cur);
  scan1<<<NODES/256,256,0,stream>>>(cur,rp,bsum);
  scan2<<<1,128,0,stream>>>(bsum,rp);
  scan3<<<NODES/256,256,0,stream>>>(rp,bsum);
  hipMemsetAsync(cur,0,NODES*sizeof(u32),stream);
  scatter_edges<<<NE/256,256,0,stream>>>(srcA,dstA,et,rp,cur,adj);

  // layer 0
  gemm_y<<<dim3(NODES/64,9),256,0,stream>>>(xh,xl,Bp,y,z);
  gather_combine<<<NODES/4,256,0,stream>>>((const u32*)y,z,adj,rp,sb,mask,(u32*)xh,(u32*)xl,out,0);
  // layer 1
  gemm_y<<<dim3(NODES/64,9),256,0,stream>>>(xh,xl,Bp+BP_LAYER,y,z);
  gather_combine<<<NODES/4,256,0,stream>>>((const u32*)y,z,adj,rp,sb+HD,mask,(u32*)xh,(u32*)xl,out,1);
}

// Round 9
// 312.175 us; speedup vs baseline: 1.8231x; 1.1270x over previous
//
#include <hip/hip_runtime.h>
#include <hip/hip_bf16.h>

#define NODES 32768
#define HD 128
#define NE 524288
#define NR 8

typedef unsigned int u32;
typedef unsigned short u16;
typedef __attribute__((ext_vector_type(8))) short bf16x8;
typedef __attribute__((ext_vector_type(4))) float f32x4;

// ---- ws byte offsets ----
#define XH_OFF   (0u)                      // bf16 hi, 8 MB
#define XL_OFF   (8u<<20)                  // bf16 lo, 8 MB
#define Y_OFF    (16u<<20)                 // bf16 y[8][NODES][128], 64 MB
#define Z_OFF    (80u<<20)                 // fp32 z[NODES][128], 16 MB
#define ADJ_OFF  (96u<<20)                 // u32 x NE (row ids)
#define RP_OFF   (98u<<20)                 // u32 x (NODES+1), block-local prefix
#define CUR_OFF  ((98u<<20)+(256u<<10))    // u32 x NODES
#define BSUM_OFF ((98u<<20)+(512u<<10))    // u32 x 129, block sums exclusive prefix
#define BP_OFF   ((98u<<20)+(640u<<10))    // packed weights bf16

#define BP_LAYER 294912                    // 9*2*16384
#define PP_ELEM  589824                    // pW packed at Bp+PP_ELEM (2 segs x 16384)

__device__ __forceinline__ float bflo(u32 u){ union{u32 i;float f;}c; c.i=u<<16; return c.f; }
__device__ __forceinline__ float bfhi(u32 u){ union{u32 i;float f;}c; c.i=u&0xffff0000u; return c.f; }
__device__ __forceinline__ u16 f2bf(float f){
  u32 u=__float_as_uint(f);
  u32 r=u + 0x7fffu + ((u>>16)&1u);
  return (u16)(r>>16);
}
__device__ __forceinline__ float bf2f(u16 h){ return __uint_as_float(((u32)h)<<16); }

__device__ __forceinline__ void gl_lds16(const void* g, void* l){
  __builtin_amdgcn_global_load_lds((const __attribute__((address_space(1))) u32*)g,
                                   (__attribute__((address_space(3))) u32*)l, 16, 0, 0);
}

// ---------------- weight prep: 2 layers x 9 tiles (8 rel + self) + pW, hi/lo segs ----
// MFMA-fragment-contiguous: k = ks*32 + q*8 + j -> (ks*128+n)*32 + q*8 + j
__global__ void prep_w(const float* __restrict__ rW, const float* __restrict__ sW,
                       const float* __restrict__ pWg, u16* __restrict__ Bp)
{
  int idx=blockIdx.x*256+threadIdx.x;           // 311296 total
  if(idx<294912){
    int l=idx/147456;
    int rem=idx%147456;
    int t=rem>>14;
    int kn=rem&16383;
    int k=kn>>7, n=kn&127;
    float w;
    if(t<8) w=rW[(((size_t)l*NR+t)*HD+n)*HD+k];
    else    w=sW[((size_t)l*HD+n)*HD+k];
    u16* base=Bp+(size_t)l*BP_LAYER+(size_t)t*32768;
    int ks=k>>5, q=(k>>3)&3, j=k&7;
    size_t off=((size_t)ks*128+n)*32+q*8+j;
    u16 hb=f2bf(w);
    u16 lb=f2bf(w-bf2f(hb));
    base[off]=hb;
    base[off+16384]=lb;
  } else {
    int kn=idx-294912;
    int k=kn>>7, n=kn&127;
    float w=pWg[(size_t)n*HD+k];
    u16* base=Bp+PP_ELEM;
    int ks=k>>5, q=(k>>3)&3, j=k&7;
    size_t off=((size_t)ks*128+n)*32+q*8+j;
    u16 hb=f2bf(w);
    u16 lb=f2bf(w-bf2f(hb));
    base[off]=hb;
    base[off+16384]=lb;
  }
}

// ---------------- embed_mfma: x = (cemb[cid]+kemb[kid]) @ pW^T + pb -> xh/xl ----------
// 128-row tile, LDS-staged hi/lo A, one barrier, same MFMA loop as gemm_y
__global__ __launch_bounds__(256,2) void embed_mfma(
    const int* __restrict__ cid, const int* __restrict__ kid,
    const float* __restrict__ cemb, const float* __restrict__ kemb,
    const u16* __restrict__ PP, const float* __restrict__ pb,
    u16* __restrict__ xh, u16* __restrict__ xl)
{
  __shared__ u16 Atile[2][128*128];   // [0]=hi [1]=lo, 64 KB, XOR-16 swizzle
  const int tid=threadIdx.x;
  const int wave=tid>>6, lane=tid&63;
  const int wm=wave>>1, wn=wave&1;
  const int q=lane>>4;
  const int d0=blockIdx.x*128;

  // ---- gather + add + split + LDS write: thread = (row=tid>>1, half=tid&1) ----
  { int r=tid>>1, half=tid&1;
    int ci=cid[d0+r], ki=kid[d0+r];
    const float* cp=cemb+(size_t)ci*HD+half*64;
    const float* kp=kemb+(size_t)ki*HD+half*64;
#pragma unroll
    for(int cc=0;cc<8;cc++){
      float4 a0=*(const float4*)(cp+cc*8);
      float4 a1=*(const float4*)(cp+cc*8+4);
      float4 b0=*(const float4*)(kp+cc*8);
      float4 b1=*(const float4*)(kp+cc*8+4);
      float v[8]={a0.x+b0.x,a0.y+b0.y,a0.z+b0.z,a0.w+b0.w,
                  a1.x+b1.x,a1.y+b1.y,a1.z+b1.z,a1.w+b1.w};
      u16 hb[8], lb[8];
#pragma unroll
      for(int j=0;j<8;j++){ hb[j]=f2bf(v[j]); lb[j]=f2bf(v[j]-bf2f(hb[j])); }
      int chunk=half*8+cc;
      int dst=r*128+(chunk^(r&15))*8;
      uint4 hv={(u32)hb[0]|((u32)hb[1]<<16),(u32)hb[2]|((u32)hb[3]<<16),
                (u32)hb[4]|((u32)hb[5]<<16),(u32)hb[6]|((u32)hb[7]<<16)};
      uint4 lv={(u32)lb[0]|((u32)lb[1]<<16),(u32)lb[2]|((u32)lb[3]<<16),
                (u32)lb[4]|((u32)lb[5]<<16),(u32)lb[6]|((u32)lb[7]<<16)};
      *(uint4*)&Atile[0][dst]=hv;
      *(uint4*)&Atile[1][dst]=lv;
    }
  }
  __syncthreads();

  f32x4 acc[4][4];
#pragma unroll
  for(int a=0;a<4;a++)
#pragma unroll
    for(int b=0;b<4;b++) acc[a][b]=(f32x4){0.f,0.f,0.f,0.f};

  // part 0: hi @ {Whi, Wlo}
#pragma unroll
  for(int ks=0;ks<4;ks++){
    bf16x8 ah[4];
#pragma unroll
    for(int tm=0;tm<4;tm++){
      int m=wm*64+tm*16+(lane&15);
      ah[tm]=*(const bf16x8*)&Atile[0][m*128+(((ks*4)+q)^(m&15))*8];
    }
#pragma unroll
    for(int s=0;s<2;s++){
      const u16* Bb=PP+s*16384;
#pragma unroll
      for(int tn=0;tn<4;tn++){
        int n=wn*64+tn*16+(lane&15);
        bf16x8 bfr=*(const bf16x8*)&Bb[((size_t)ks*128+n)*32+q*8];
#pragma unroll
        for(int tm=0;tm<4;tm++)
          acc[tm][tn]=__builtin_amdgcn_mfma_f32_16x16x32_bf16(ah[tm],bfr,acc[tm][tn],0,0,0);
      }
    }
  }
  // part 1: lo @ Whi
#pragma unroll
  for(int ks=0;ks<4;ks++){
    bf16x8 al[4];
#pragma unroll
    for(int tm=0;tm<4;tm++){
      int m=wm*64+tm*16+(lane&15);
      al[tm]=*(const bf16x8*)&Atile[1][m*128+(((ks*4)+q)^(m&15))*8];
    }
#pragma unroll
    for(int tn=0;tn<4;tn++){
      int n=wn*64+tn*16+(lane&15);
      bf16x8 bfr=*(const bf16x8*)&PP[((size_t)ks*128+n)*32+q*8];
#pragma unroll
      for(int tm=0;tm<4;tm++)
        acc[tm][tn]=__builtin_amdgcn_mfma_f32_16x16x32_bf16(al[tm],bfr,acc[tm][tn],0,0,0);
    }
  }

  // epilogue: +pb, split hi/lo; C/D layout col=lane&15, row=(lane>>4)*4+reg
#pragma unroll
  for(int tn=0;tn<4;tn++){
    int n=wn*64+tn*16+(lane&15);
    float b=pb[n];
#pragma unroll
    for(int tm=0;tm<4;tm++){
      int rbase=d0+wm*64+tm*16+q*4;
#pragma unroll
      for(int r=0;r<4;r++){
        float v=acc[tm][tn][r]+b;
        u16 hb=f2bf(v);
        u16 lb=f2bf(v-bf2f(hb));
        xh[(size_t)(rbase+r)*HD+n]=hb;
        xl[(size_t)(rbase+r)*HD+n]=lb;
      }
    }
  }
}

// ---------------- CSR build ----------------
__global__ void count_deg(const int* __restrict__ dst, u32* __restrict__ cnt){
  int e=blockIdx.x*256+threadIdx.x;
  atomicAdd(&cnt[dst[e]],1u);
}

__global__ void scan1(u32* __restrict__ cnt, u32* __restrict__ rp, u32* __restrict__ bsum){
  __shared__ u32 sh[256];
  int t=threadIdx.x; int base=blockIdx.x*256;
  u32 v=cnt[base+t]; sh[t]=v;
  cnt[base+t]=0u;                       // re-zero cur for scatter
  __syncthreads();
  for(int off=1;off<256;off<<=1){
    u32 tv=(t>=off)?sh[t-off]:0u; __syncthreads();
    sh[t]+=tv; __syncthreads();
  }
  rp[base+t]=sh[t]-v;
  if(t==255) bsum[blockIdx.x]=sh[255];
}

__global__ void scan2(u32* __restrict__ bsum, u32* __restrict__ rp){
  __shared__ u32 sh[128];
  int t=threadIdx.x;
  u32 v=bsum[t]; sh[t]=v; __syncthreads();
  for(int off=1;off<128;off<<=1){
    u32 tv=(t>=off)?sh[t-off]:0u; __syncthreads();
    sh[t]+=tv; __syncthreads();
  }
  bsum[t]=sh[t]-v;
  if(t==0){ rp[NODES]=NE; bsum[128]=0u; }
}

__global__ void scatter_edges(const int* __restrict__ src, const int* __restrict__ dst,
                              const int* __restrict__ et, const u32* __restrict__ rp,
                              const u32* __restrict__ bsum,
                              u32* __restrict__ cur, u32* __restrict__ adj){
  int e=blockIdx.x*256+threadIdx.x;
  int d=dst[e];
  u32 pos=atomicAdd(&cur[d],1u);
  adj[rp[d]+bsum[d>>8]+pos]=(u32)(et[e]*NODES+src[e]);   // precomputed y-row id
}

// ---------------- gemm_y: 128-row tile, ONE t per block, ONE barrier ----------------
// y[t] = x @ W_t^T (t<8, bf16 out), z = x @ selfW^T (t==8, fp32 out)
// grid (NODES/128, 9); waves 2x2; LDS xhi+xlo 64 KB, single __syncthreads
__global__ __launch_bounds__(256,2) void gemm_y(
    const u16* __restrict__ xhi, const u16* __restrict__ xlo,
    const u16* __restrict__ Bt, u16* __restrict__ y, float* __restrict__ z)
{
  __shared__ u16 Atile[2][128*128];   // [0]=hi [1]=lo; row=256B, XOR-16 swizzle
  const int tid=threadIdx.x;
  const int wave=tid>>6, lane=tid&63;
  const int wm=wave>>1, wn=wave&1;
  const int q=lane>>4;
  const int d0=blockIdx.x*128;
  const int t=blockIdx.y;
  const u16* Btile=Bt+(size_t)t*32768;

  const int st_c  = lane&15;
  const int st_rin= lane>>4;

#pragma unroll
  for(int i=0;i<8;i++){
    int rbase=wave*32+i*4;
    int r=rbase+st_rin;
    int g=st_c ^ (r&15);
    gl_lds16(xhi+(size_t)(d0+r)*HD+g*8, &Atile[0][rbase*128]);
  }
#pragma unroll
  for(int i=0;i<8;i++){
    int rbase=wave*32+i*4;
    int r=rbase+st_rin;
    int g=st_c ^ (r&15);
    gl_lds16(xlo+(size_t)(d0+r)*HD+g*8, &Atile[1][rbase*128]);
  }
  __syncthreads();

  f32x4 acc[4][4];
#pragma unroll
  for(int a=0;a<4;a++)
#pragma unroll
    for(int b=0;b<4;b++) acc[a][b]=(f32x4){0.f,0.f,0.f,0.f};

  // part 0: xhi @ {Whi, Wlo}
#pragma unroll
  for(int ks=0;ks<4;ks++){
    bf16x8 ah[4];
#pragma unroll
    for(int tm=0;tm<4;tm++){
      int m=wm*64+tm*16+(lane&15);
      ah[tm]=*(const bf16x8*)&Atile[0][m*128+(((ks*4)+q)^(m&15))*8];
    }
#pragma unroll
    for(int s=0;s<2;s++){
      const u16* Bb=Btile+s*16384;
#pragma unroll
      for(int tn=0;tn<4;tn++){
        int n=wn*64+tn*16+(lane&15);
        bf16x8 bfr=*(const bf16x8*)&Bb[((size_t)ks*128+n)*32+q*8];
#pragma unroll
        for(int tm=0;tm<4;tm++)
          acc[tm][tn]=__builtin_amdgcn_mfma_f32_16x16x32_bf16(ah[tm],bfr,acc[tm][tn],0,0,0);
      }
    }
  }
  // part 1: xlo @ Whi
#pragma unroll
  for(int ks=0;ks<4;ks++){
    bf16x8 al[4];
#pragma unroll
    for(int tm=0;tm<4;tm++){
      int m=wm*64+tm*16+(lane&15);
      al[tm]=*(const bf16x8*)&Atile[1][m*128+(((ks*4)+q)^(m&15))*8];
    }
#pragma unroll
    for(int tn=0;tn<4;tn++){
      int n=wn*64+tn*16+(lane&15);
      bf16x8 bfr=*(const bf16x8*)&Btile[((size_t)ks*128+n)*32+q*8];
#pragma unroll
      for(int tm=0;tm<4;tm++)
        acc[tm][tn]=__builtin_amdgcn_mfma_f32_16x16x32_bf16(al[tm],bfr,acc[tm][tn],0,0,0);
    }
  }

  // epilogue: C/D layout col=lane&15, row=(lane>>4)*4+reg
  if(t<8){
    u16* yt=y+((size_t)t*NODES+d0)*HD;
#pragma unroll
    for(int tn=0;tn<4;tn++){
      int n=wn*64+tn*16+(lane&15);
#pragma unroll
      for(int tm=0;tm<4;tm++){
        int rbase=wm*64+tm*16+q*4;
#pragma unroll
        for(int r=0;r<4;r++)
          yt[(size_t)(rbase+r)*HD+n]=f2bf(acc[tm][tn][r]);
      }
    }
  } else {
    float* zt=z+(size_t)d0*HD;
#pragma unroll
    for(int tn=0;tn<4;tn++){
      int n=wn*64+tn*16+(lane&15);
#pragma unroll
      for(int tm=0;tm<4;tm++){
        int rbase=wm*64+tm*16+q*4;
#pragma unroll
        for(int r=0;r<4;r++)
          zt[(size_t)(rbase+r)*HD+n]=acc[tm][tn][r];
      }
    }
  }
}

// ---------------- gather_combine: agg = (1/deg) * sum_e y[row_e]; out = relu(z+agg+b)
// wave per node; lane=(sub=lane>>5, c=lane&31); uint2 loads -> 2 rows per issue;
// adj read once per 64 edges (coalesced) and broadcast via shfl.
__global__ __launch_bounds__(256) void gather_combine(
    const uint2* __restrict__ yy, const float* __restrict__ z,
    const u32* __restrict__ adj, const u32* __restrict__ rp, const u32* __restrict__ bsum,
    const float* __restrict__ sb, const int* __restrict__ mask,
    u32* __restrict__ xh, u32* __restrict__ xl, float* __restrict__ outf, int last)
{
  const int wave=threadIdx.x>>6, lane=threadIdx.x&63;
  const int node=blockIdx.x*4+wave;
  const int sub=lane>>5, c=lane&31;
  const int beg=(int)(rp[node]+bsum[node>>8]);
  const int end=(int)(rp[node+1]+bsum[(node+1)>>8]);
  float a0=0.f,a1=0.f,a2=0.f,a3=0.f;

  for(int base=beg; base<end; base+=64){
    int nk=end-base; if(nk>64) nk=64;
    u32 adjv = (lane<nk) ? adj[base+lane] : 0u;
    int i=0;
    for(; i+16<=nk; i+=16){
      uint2 vv[8];
#pragma unroll
      for(int j=0;j<8;j++){
        u32 row=(u32)__shfl((int)adjv, i+j*2+sub);
        vv[j]=yy[(size_t)row*32+c];
      }
#pragma unroll
      for(int j=0;j<8;j++){
        a0+=bflo(vv[j].x); a1+=bfhi(vv[j].x);
        a2+=bflo(vv[j].y); a3+=bfhi(vv[j].y);
      }
    }
    for(; i+2<=nk; i+=2){
      u32 row=(u32)__shfl((int)adjv, i+sub);
      uint2 v=yy[(size_t)row*32+c];
      a0+=bflo(v.x); a1+=bfhi(v.x); a2+=bflo(v.y); a3+=bfhi(v.y);
    }
    if(i<nk){
      u32 row=(u32)__shfl((int)adjv, i);
      if(sub==0){
        uint2 v=yy[(size_t)row*32+c];
        a0+=bflo(v.x); a1+=bfhi(v.x); a2+=bflo(v.y); a3+=bfhi(v.y);
      }
    }
  }

  a0+=__shfl_xor(a0,32); a1+=__shfl_xor(a1,32);
  a2+=__shfl_xor(a2,32); a3+=__shfl_xor(a3,32);

  if(sub==0){
    float inv=1.f/fmaxf((float)(end-beg),1.f);
    float4 zz=*(const float4*)&z[(size_t)node*HD+c*4];
    float4 bb=*(const float4*)&sb[c*4];
    float v0=fmaxf(zz.x+a0*inv+bb.x,0.f);
    float v1=fmaxf(zz.y+a1*inv+bb.y,0.f);
    float v2=fmaxf(zz.z+a2*inv+bb.z,0.f);
    float v3=fmaxf(zz.w+a3*inv+bb.w,0.f);
    if(last){
      float mk=(float)mask[node];
      float4 o={v0*mk,v1*mk,v2*mk,v3*mk};
      *(float4*)&outf[(size_t)node*HD+c*4]=o;
    } else {
      u16 h0=f2bf(v0), h1=f2bf(v1), h2=f2bf(v2), h3=f2bf(v3);
      u16 l0=f2bf(v0-bf2f(h0)), l1=f2bf(v1-bf2f(h1));
      u16 l2=f2bf(v2-bf2f(h2)), l3=f2bf(v3-bf2f(h3));
      uint2 hv={(u32)h0|((u32)h1<<16),(u32)h2|((u32)h3<<16)};
      uint2 lv={(u32)l0|((u32)l1<<16),(u32)l2|((u32)l3<<16)};
      *(uint2*)&xh[(size_t)node*64+c*2]=hv;
      *(uint2*)&xl[(size_t)node*64+c*2]=lv;
    }
  }
}

extern "C" void kernel_launch(void* const* d_in, const int* in_sizes, int n_in,
                              void* d_out, int out_size, void* d_ws, size_t ws_size,
                              hipStream_t stream)
{
  (void)in_sizes; (void)n_in; (void)out_size; (void)ws_size;
  const int*   cid =(const int*)  d_in[0];
  const int*   kid =(const int*)  d_in[1];
  const int*   mask=(const int*)  d_in[2];
  const int*   ei  =(const int*)  d_in[3];
  const int*   et  =(const int*)  d_in[4];
  const float* cemb=(const float*)d_in[5];
  const float* kemb=(const float*)d_in[6];
  const float* pW  =(const float*)d_in[7];
  const float* pb  =(const float*)d_in[8];
  const float* sW  =(const float*)d_in[9];
  const float* sb  =(const float*)d_in[10];
  const float* rW  =(const float*)d_in[11];
  float* out=(float*)d_out;
  char*  ws =(char*)d_ws;

  u16* xh =(u16*)(ws+XH_OFF);
  u16* xl =(u16*)(ws+XL_OFF);
  u16* y  =(u16*)(ws+Y_OFF);
  float* z=(float*)(ws+Z_OFF);
  u32* adj =(u32*)(ws+ADJ_OFF);
  u32* rp  =(u32*)(ws+RP_OFF);
  u32* cur =(u32*)(ws+CUR_OFF);
  u32* bsum=(u32*)(ws+BSUM_OFF);
  u16* Bp  =(u16*)(ws+BP_OFF);
  const int* srcA=ei;
  const int* dstA=ei+NE;

  hipMemsetAsync(cur,0,NODES*sizeof(u32),stream);
  prep_w<<<1216,256,0,stream>>>(rW,sW,pW,Bp);
  embed_mfma<<<NODES/128,256,0,stream>>>(cid,kid,cemb,kemb,Bp+PP_ELEM,pb,xh,xl);
  count_deg<<<NE/256,256,0,stream>>>(dstA,cur);
  scan1<<<NODES/256,256,0,stream>>>(cur,rp,bsum);
  scan2<<<1,128,0,stream>>>(bsum,rp);
  scatter_edges<<<NE/256,256,0,stream>>>(srcA,dstA,et,rp,bsum,cur,adj);

  // layer 0
  gemm_y<<<dim3(NODES/128,9),256,0,stream>>>(xh,xl,Bp,y,z);
  gather_combine<<<NODES/4,256,0,stream>>>((const uint2*)y,z,adj,rp,bsum,sb,mask,(u32*)xh,(u32*)xl,out,0);
  // layer 1
  gemm_y<<<dim3(NODES/128,9),256,0,stream>>>(xh,xl,Bp+BP_LAYER,y,z);
  gather_combine<<<NODES/4,256,0,stream>>>((const uint2*)y,z,adj,rp,bsum,sb+HD,mask,(u32*)xh,(u32*)xl,out,1);
}